// Round 3
// baseline (434.260 us; speedup 1.0000x reference)
//
#include <hip/hip_runtime.h>
#include <math.h>

// x: (16, 52, 256, 256) fp32, GROUPS=52, cpg=1. 832 independent slices of
// 65536 elements: argmax+mean -> sim stats -> gated output.
//
// Round-2 post-mortem: the reg-resident single-kernel holds 64 payload VGPRs
// -> 1 block/CU -> load/compute/store phases serialize chip-wide (lockstep)
// and the 832-block grid has a 25% ragged tail. Measured 2.35 TB/s effective,
// VALUBusy 21%, occupancy 33% -- latency/serialization-bound, not BW-bound.
//
// This version: 3 streaming passes, 3328 blocks x 256 threads (64KB strip
// each), per-slice partials in d_ws (deterministic, no atomics). Every pass
// is a pure memory stream at ~full occupancy; passes 2-3 re-read x from the
// 256MB L3 (x=218MB fits; round-2 FETCH=106GB proves x stays L3-resident).
// The separable Gaussian row/col tables (320 exps/block) make sweeps pure FMA.
#define Gn 52
#define Hn 256
#define Wn 256
#define HW (Hn * Wn)       // 65536
#define HW4 (HW / 4)       // 16384
#define NSLICE 832         // B*G
#define SPB 4              // strips per slice
#define NBLK (NSLICE * SPB)
#define TPB 256
#define STRIP4 (HW4 / SPB) // 4096 float4 per strip
#define VPT (STRIP4 / TPB) // 16 float4 per thread
#define WSS 24             // ws floats per slice: amax[4], idx[4], sum[4], s1[4], s2[4]

typedef float vf4 __attribute__((ext_vector_type(4)));

// ---------------- pass 1: per-strip argmax (first occurrence) + sum ----------
__global__ __launch_bounds__(TPB) void k_p1(
    const float4* __restrict__ x4, float* __restrict__ ws)
{
    const int blk = blockIdx.x;
    const int bg = blk >> 2, q = blk & 3;
    const int t = threadIdx.x;
    const int wave = t >> 6, lane = t & 63;
    const float4* xp = x4 + (size_t)bg * HW4 + q * STRIP4;

    float vmax = -INFINITY; int imax = 0x7fffffff; float sum = 0.f;
    #pragma unroll
    for (int kk = 0; kk < VPT; kk += 4) {
        float4 b[4];
        #pragma unroll
        for (int u = 0; u < 4; ++u) b[u] = xp[t + (kk + u) * TPB];
        #pragma unroll
        for (int u = 0; u < 4; ++u) {
            int e = (q * STRIP4 + t + (kk + u) * TPB) * 4;  // slice-local idx
            float4 v = b[u];
            sum += (v.x + v.y) + (v.z + v.w);
            if (v.x > vmax) { vmax = v.x; imax = e; }
            if (v.y > vmax) { vmax = v.y; imax = e + 1; }
            if (v.z > vmax) { vmax = v.z; imax = e + 2; }
            if (v.w > vmax) { vmax = v.w; imax = e + 3; }
        }
    }
    #pragma unroll
    for (int off = 32; off > 0; off >>= 1) {
        float ov = __shfl_down(vmax, off);
        int   oi = __shfl_down(imax, off);
        float os = __shfl_down(sum,  off);
        sum += os;
        if (ov > vmax || (ov == vmax && oi < imax)) { vmax = ov; imax = oi; }
    }
    __shared__ float rv[4]; __shared__ int ri[4]; __shared__ float rs[4];
    if (lane == 0) { rv[wave] = vmax; ri[wave] = imax; rs[wave] = sum; }
    __syncthreads();
    if (t == 0) {
        float bv = rv[0]; int bi = ri[0]; float bs = rs[0];
        #pragma unroll
        for (int i = 1; i < 4; ++i) {
            bs += rs[i];
            if (rv[i] > bv || (rv[i] == bv && ri[i] < bi)) { bv = rv[i]; bi = ri[i]; }
        }
        float* w = ws + (size_t)bg * WSS;
        w[q]     = bv;
        w[4 + q] = (float)bi;   // < 65536: exact in fp32
        w[8 + q] = bs;
    }
}

// combine the 4 strip partials of a slice (redundant per thread, cheap)
__device__ __forceinline__ void combine_amax(
    const float* __restrict__ w, float& qrow, float& qcol, float& qval, float& gap)
{
    float bv = w[0], bif = w[4], bs = w[8];
    #pragma unroll
    for (int i = 1; i < 4; ++i) {
        float vv = w[i], ii = w[4 + i];
        if (vv > bv || (vv == bv && ii < bif)) { bv = vv; bif = ii; }
        bs += w[8 + i];
    }
    int bi = (int)bif;
    qrow = (float)(bi >> 8);
    qcol = (float)(bi & 255);
    qval = bv;
    gap  = bs * (1.f / (float)HW);
}

// ---------------- pass 2: sim statistics (s1, s2) per strip ------------------
__global__ __launch_bounds__(TPB) void k_p2(
    const float4* __restrict__ x4, float* __restrict__ ws,
    const float* __restrict__ one_, const float* __restrict__ zero,
    const float* __restrict__ theta, const float* __restrict__ scale)
{
    const int blk = blockIdx.x;
    const int bg = blk >> 2, q = blk & 3;
    const int g = bg % Gn;
    const int t = threadIdx.x;
    const int wave = t >> 6, lane = t & 63;
    const float4* xp = x4 + (size_t)bg * HW4 + q * STRIP4;
    float* w = ws + (size_t)bg * WSS;

    float qrow, qcol, qval, gap;
    combine_amax(w, qrow, qcol, qval, gap);

    const float sigma   = scale[0];
    const float inv2s2  = 0.5f / (sigma * sigma);
    const float lognorm = -logf(sigma) - 0.9189385332046727f; // -0.5*log(2pi)
    const float A05 = 0.5f * zero[g] * qval;
    const float Bc  = one_[g] * gap;
    const float th0 = theta[0], th1 = theta[1];

    __shared__ float wcol[256];   // 0.5*A*gc(c)
    __shared__ float urow[64];    // 0.5*A*gr(r) + B, rows of this strip
    {
        float zc = ((float)t - qcol) * th1;
        wcol[t] = A05 * __expf(lognorm - zc * zc * inv2s2);
        if (t < 64) {
            float zr = ((float)(64 * q + t) - qrow) * th0;
            urow[t] = A05 * __expf(lognorm - zr * zr * inv2s2) + Bc;
        }
    }
    __syncthreads();

    const float4 cw = *reinterpret_cast<const float4*>(&wcol[(4 * t) & 255]);

    float s1 = 0.f, s2 = 0.f;
    #pragma unroll
    for (int kk = 0; kk < VPT; kk += 4) {
        float4 b[4];
        #pragma unroll
        for (int u = 0; u < 4; ++u) b[u] = xp[t + (kk + u) * TPB];
        #pragma unroll
        for (int u = 0; u < 4; ++u) {
            const float ur = urow[4 * (kk + u) + (t >> 6)];
            float4 v = b[u];
            float f, sim;
            f = ur + cw.x; sim = f * v.x; s1 += sim; s2 = fmaf(sim, sim, s2);
            f = ur + cw.y; sim = f * v.y; s1 += sim; s2 = fmaf(sim, sim, s2);
            f = ur + cw.z; sim = f * v.z; s1 += sim; s2 = fmaf(sim, sim, s2);
            f = ur + cw.w; sim = f * v.w; s1 += sim; s2 = fmaf(sim, sim, s2);
        }
    }
    #pragma unroll
    for (int off = 32; off > 0; off >>= 1) {
        s1 += __shfl_down(s1, off);
        s2 += __shfl_down(s2, off);
    }
    __shared__ float r1[4], r2[4];
    if (lane == 0) { r1[wave] = s1; r2[wave] = s2; }
    __syncthreads();
    if (t == 0) {
        float S1 = r1[0] + r1[1] + r1[2] + r1[3];
        float S2 = r2[0] + r2[1] + r2[2] + r2[3];
        w[12 + q] = S1;
        w[16 + q] = S2;
    }
}

// ---------------- pass 3: normalize + sigmoid gate + output ------------------
__global__ __launch_bounds__(TPB) void k_p3(
    const float4* __restrict__ x4, const float* __restrict__ ws,
    const float* __restrict__ weight, const float* __restrict__ bias,
    const float* __restrict__ one_, const float* __restrict__ zero,
    const float* __restrict__ theta, const float* __restrict__ scale,
    float4* __restrict__ out4)
{
    const int blk = blockIdx.x;
    const int bg = blk >> 2, q = blk & 3;
    const int g = bg % Gn;
    const int t = threadIdx.x;
    const size_t base4 = (size_t)bg * HW4 + q * STRIP4;
    const float4* xp = x4 + base4;
    const float* w = ws + (size_t)bg * WSS;

    float qrow, qcol, qval, gap;
    combine_amax(w, qrow, qcol, qval, gap);
    const float S1 = (w[12] + w[13]) + (w[14] + w[15]);
    const float S2 = (w[16] + w[17]) + (w[18] + w[19]);

    const float sigma   = scale[0];
    const float inv2s2  = 0.5f / (sigma * sigma);
    const float lognorm = -logf(sigma) - 0.9189385332046727f;
    const float A05 = 0.5f * zero[g] * qval;
    const float Bc  = one_[g] * gap;
    const float th0 = theta[0], th1 = theta[1];

    const float mean = S1 * (1.f / (float)HW);
    float var = (S2 - S1 * mean) * (1.f / (float)(HW - 1));
    var = fmaxf(var, 0.f);
    const float wsc = weight[g] / (sqrtf(var) + 1e-5f);
    const float wb  = fmaf(-mean, wsc, bias[g]);   // ctx = sim*wsc + wb

    __shared__ float wcol[256];
    __shared__ float urow[64];
    {
        float zc = ((float)t - qcol) * th1;
        wcol[t] = A05 * __expf(lognorm - zc * zc * inv2s2);
        if (t < 64) {
            float zr = ((float)(64 * q + t) - qrow) * th0;
            urow[t] = A05 * __expf(lognorm - zr * zr * inv2s2) + Bc;
        }
    }
    __syncthreads();

    const float4 cw = *reinterpret_cast<const float4*>(&wcol[(4 * t) & 255]);

    #pragma unroll
    for (int kk = 0; kk < VPT; kk += 4) {
        float4 b[4];
        #pragma unroll
        for (int u = 0; u < 4; ++u) b[u] = xp[t + (kk + u) * TPB];
        #pragma unroll
        for (int u = 0; u < 4; ++u) {
            const float ur = urow[4 * (kk + u) + (t >> 6)];
            float4 v = b[u];
            vf4 o;
            float f, sim, ctx;
            f = ur + cw.x; sim = f * v.x; ctx = fmaf(sim, wsc, wb);
            o.x = v.x * __builtin_amdgcn_rcpf(1.f + __expf(-ctx));
            f = ur + cw.y; sim = f * v.y; ctx = fmaf(sim, wsc, wb);
            o.y = v.y * __builtin_amdgcn_rcpf(1.f + __expf(-ctx));
            f = ur + cw.z; sim = f * v.z; ctx = fmaf(sim, wsc, wb);
            o.z = v.z * __builtin_amdgcn_rcpf(1.f + __expf(-ctx));
            f = ur + cw.w; sim = f * v.w; ctx = fmaf(sim, wsc, wb);
            o.w = v.w * __builtin_amdgcn_rcpf(1.f + __expf(-ctx));
            __builtin_nontemporal_store(o,
                reinterpret_cast<vf4*>(out4 + base4 + t + (kk + u) * TPB));
        }
    }
}

extern "C" void kernel_launch(void* const* d_in, const int* in_sizes, int n_in,
                              void* d_out, int out_size, void* d_ws, size_t ws_size,
                              hipStream_t stream) {
    const float* x      = (const float*)d_in[0];
    const float* weight = (const float*)d_in[1];
    const float* bias   = (const float*)d_in[2];
    const float* one_   = (const float*)d_in[3];
    const float* zero   = (const float*)d_in[4];
    const float* theta  = (const float*)d_in[5];
    const float* scale  = (const float*)d_in[6];
    float* out = (float*)d_out;
    float* ws  = (float*)d_ws;   // needs 832*24*4 = 80 KB

    k_p1<<<NBLK, TPB, 0, stream>>>((const float4*)x, ws);
    k_p2<<<NBLK, TPB, 0, stream>>>((const float4*)x, ws, one_, zero, theta, scale);
    k_p3<<<NBLK, TPB, 0, stream>>>((const float4*)x, ws, weight, bias, one_, zero,
                                   theta, scale, (float4*)out);
}

// Round 4
// 387.900 us; speedup vs baseline: 1.1195x; 1.1195x over previous
//
#include <hip/hip_runtime.h>
#include <math.h>

// x: (16, 52, 256, 256) fp32. 832 independent 64K-element slices:
// argmax+mean -> sim stats -> gated output.
//
// Round-3 post-mortem: streaming 3-pass = 3 reads + 1 write = 872 MB at
// ~HBM rate (L3 re-reads are NOT faster) = the 138us floor we already had.
// So x must be read once -> payload on-CU. A slice (256KB) is 50% of the
// per-CU register file -> 1 block/CU, and round-2's loss vs the 69us
// traffic floor is chip-wide phase lockstep (load | compute | store).
//
// This version: persistent pipeline. 208 blocks x 4 slices each (832 exact,
// no tail). Current slice in regs (16 float4/thread); next slice's first
// 9/16 chunks stream into 144KB LDS via global_load_lds (no regs, stays in
// flight across RAW s_barriers - __syncthreads would drain vmcnt(0) and
// kill the overlap). Slice switch: counted s_waitcnt vmcnt(16) (9 prefetch
// loads are oldest among 9 + 16 outstanding stores) -> ds_read payload ->
// 7 direct loads for the rest. Reductions use raw barrier + lgkmcnt only.
#define Gn 52
#define Hn 256
#define Wn 256
#define HW (Hn * Wn)     // 65536
#define HW4 (HW / 4)     // 16384
#define NSLICE 832
#define NBLK 208         // x NPER = 832 exactly
#define NPER 4
#define TPB 1024
#define VPT 16           // float4 per thread
#define LCH 9            // chunks staged in LDS (144 KB); VPT-LCH direct

typedef float vf4 __attribute__((ext_vector_type(4)));
typedef __attribute__((address_space(3))) unsigned int lds_u32;
typedef __attribute__((address_space(1))) const unsigned int glb_u32;

// raw barrier: own-wave LDS writes drained, NO vmcnt drain (prefetch lives)
#define BAR() do { asm volatile("s_waitcnt lgkmcnt(0)" ::: "memory"); \
                   __builtin_amdgcn_s_barrier();                      \
                   asm volatile("" ::: "memory"); } while (0)

__global__ __launch_bounds__(TPB, 4) void k_fused(
    const float4* __restrict__ x4,
    const float* __restrict__ weight, const float* __restrict__ bias,
    const float* __restrict__ one_,  const float* __restrict__ zero,
    const float* __restrict__ theta, const float* __restrict__ scale,
    float4* __restrict__ out4)
{
    __shared__ float4 lds4[LCH * TPB];          // 144 KB prefetch buffer
    __shared__ __align__(16) float wcol[256];   // 0.5*A*gc(c)
    __shared__ float urow[256];                 // 0.5*A*gr(r) + B
    __shared__ float rv[16];
    __shared__ int   ri[16];
    __shared__ float r1[16];
    __shared__ float r2[16];
    __shared__ float bc[2];                     // mean, wsc

    const int t    = threadIdx.x;
    const int wave = t >> 6;
    const int lane = t & 63;

    const float sigma   = scale[0];
    const float inv2s2  = 0.5f / (sigma * sigma);
    const float lognorm = -logf(sigma) - 0.9189385332046727f; // -0.5*log(2pi)
    const float th0 = theta[0], th1 = theta[1];

    #pragma unroll
    for (int it = 0; it < NPER; ++it) {
        const int bg = blockIdx.x * NPER + it;
        const int g  = bg % Gn;
        const size_t base4 = (size_t)bg * HW4;
        const float4* xp = x4 + base4;

        // ---- acquire payload for this slice ----
        float4 v[VPT];
        if (it == 0) {
            #pragma unroll
            for (int k = 0; k < VPT; ++k) v[k] = xp[t + k * TPB];
        } else {
            // 9 prefetch loads are the OLDEST of (9 prefetch + 16 stores)
            asm volatile("s_waitcnt vmcnt(16)" ::: "memory");
            __builtin_amdgcn_sched_barrier(0);
            #pragma unroll
            for (int k = 0; k < LCH; ++k) v[k] = lds4[k * TPB + t];
            #pragma unroll
            for (int k = LCH; k < VPT; ++k) v[k] = xp[t + k * TPB];
            // lds4 fully read before prefetch may overwrite it
            asm volatile("s_waitcnt lgkmcnt(0)" ::: "memory");
            __builtin_amdgcn_sched_barrier(0);
        }
        // ---- issue async prefetch of next slice's LDS chunks ----
        if (it + 1 < NPER) {
            const float4* xn = x4 + (size_t)(bg + 1) * HW4;
            #pragma unroll
            for (int k = 0; k < LCH; ++k) {
                __builtin_amdgcn_global_load_lds(
                    (glb_u32*)(xn + k * TPB + t),
                    (lds_u32*)&lds4[k * TPB + (t & ~63)], 16, 0, 0);
            }
        }

        // ---- sweep 1: argmax (first occurrence) + sum, 2-way ILP ----
        // element e = (t + k*TPB)*4: row = 16k + wave, col = 4*lane + j
        float vmaxA = -INFINITY, vmaxB = -INFINITY;
        int   imaxA = 0x7fffffff, imaxB = 0x7fffffff;
        float sumA = 0.f, sumB = 0.f;
        #pragma unroll
        for (int k = 0; k < VPT; k += 2) {
            int e0 = (t + k * TPB) * 4;
            float4 q0 = v[k];
            sumA += (q0.x + q0.y) + (q0.z + q0.w);
            if (q0.x > vmaxA) { vmaxA = q0.x; imaxA = e0; }
            if (q0.y > vmaxA) { vmaxA = q0.y; imaxA = e0 + 1; }
            if (q0.z > vmaxA) { vmaxA = q0.z; imaxA = e0 + 2; }
            if (q0.w > vmaxA) { vmaxA = q0.w; imaxA = e0 + 3; }
            int e1 = (t + (k + 1) * TPB) * 4;
            float4 q1 = v[k + 1];
            sumB += (q1.x + q1.y) + (q1.z + q1.w);
            if (q1.x > vmaxB) { vmaxB = q1.x; imaxB = e1; }
            if (q1.y > vmaxB) { vmaxB = q1.y; imaxB = e1 + 1; }
            if (q1.z > vmaxB) { vmaxB = q1.z; imaxB = e1 + 2; }
            if (q1.w > vmaxB) { vmaxB = q1.w; imaxB = e1 + 3; }
        }
        float sum = sumA + sumB;
        float vmax = vmaxA; int imax = imaxA;
        if (vmaxB > vmax || (vmaxB == vmax && imaxB < imax)) { vmax = vmaxB; imax = imaxB; }
        #pragma unroll
        for (int off = 32; off > 0; off >>= 1) {
            float ov = __shfl_down(vmax, off);
            int   oi = __shfl_down(imax, off);
            float os = __shfl_down(sum,  off);
            sum += os;
            if (ov > vmax || (ov == vmax && oi < imax)) { vmax = ov; imax = oi; }
        }
        if (lane == 0) { rv[wave] = vmax; ri[wave] = imax; r1[wave] = sum; }
        BAR();   // B1: partials visible

        // ---- wave0: combine partials + build Gaussian tables (8 exp/lane) ----
        if (wave == 0) {
            float bv = (lane < 16) ? rv[lane] : -INFINITY;
            int   bi = (lane < 16) ? ri[lane] : 0x7fffffff;
            float bs = (lane < 16) ? r1[lane] : 0.f;
            #pragma unroll
            for (int off = 8; off > 0; off >>= 1) {
                float ov = __shfl_down(bv, off);
                int   oi = __shfl_down(bi, off);
                float os = __shfl_down(bs, off);
                bs += os;
                if (ov > bv || (ov == bv && oi < bi)) { bv = ov; bi = oi; }
            }
            bv = __shfl(bv, 0); bi = __shfl(bi, 0); bs = __shfl(bs, 0);
            const float qrow = (float)(bi >> 8);
            const float qcol = (float)(bi & 255);
            const float A05  = 0.5f * zero[g] * bv;
            const float Bc   = one_[g] * (bs * (1.f / (float)HW));
            #pragma unroll
            for (int j = 0; j < 4; ++j) {
                int c = (lane << 2) + j;
                float zc = ((float)c - qcol) * th1;
                wcol[c] = A05 * __expf(lognorm - zc * zc * inv2s2);
                float zr = ((float)c - qrow) * th0;
                urow[c] = A05 * __expf(lognorm - zr * zr * inv2s2) + Bc;
            }
        }
        BAR();   // B2: tables ready

        // per-thread columns are k-invariant (c = 4*lane + j for every k)
        const float4 cw = *reinterpret_cast<const float4*>(&wcol[lane << 2]);

        // ---- sweep 2: sim statistics (pure FMA) ----
        float s1 = 0.f, s2 = 0.f;
        #pragma unroll
        for (int k = 0; k < VPT; ++k) {
            const float ur = urow[16 * k + wave];
            float4 q = v[k];
            float f, sim;
            f = ur + cw.x; sim = f * q.x; s1 += sim; s2 = fmaf(sim, sim, s2);
            f = ur + cw.y; sim = f * q.y; s1 += sim; s2 = fmaf(sim, sim, s2);
            f = ur + cw.z; sim = f * q.z; s1 += sim; s2 = fmaf(sim, sim, s2);
            f = ur + cw.w; sim = f * q.w; s1 += sim; s2 = fmaf(sim, sim, s2);
        }
        #pragma unroll
        for (int off = 32; off > 0; off >>= 1) {
            s1 += __shfl_down(s1, off);
            s2 += __shfl_down(s2, off);
        }
        if (lane == 0) { r1[wave] = s1; r2[wave] = s2; }
        BAR();   // B3: stat partials visible

        if (wave == 0) {
            float S1 = (lane < 16) ? r1[lane] : 0.f;
            float S2 = (lane < 16) ? r2[lane] : 0.f;
            #pragma unroll
            for (int off = 8; off > 0; off >>= 1) {
                S1 += __shfl_down(S1, off);
                S2 += __shfl_down(S2, off);
            }
            if (lane == 0) {
                float mean = S1 * (1.f / (float)HW);
                float var  = (S2 - S1 * mean) * (1.f / (float)(HW - 1));
                var = fmaxf(var, 0.f);
                bc[0] = mean;
                bc[1] = weight[g] / (sqrtf(var) + 1e-5f);
            }
        }
        BAR();   // B4: mean/wsc ready

        const float mean = bc[0], wsc = bc[1];
        const float wb = fmaf(-mean, wsc, bias[g]);   // ctx = sim*wsc + wb

        // ---- sweep 3: gated output, non-temporal stores ----
        #pragma unroll
        for (int k = 0; k < VPT; ++k) {
            const float ur = urow[16 * k + wave];
            float4 q = v[k];
            vf4 o;
            float f, sim, ctx;
            f = ur + cw.x; sim = f * q.x; ctx = fmaf(sim, wsc, wb);
            o.x = q.x * __builtin_amdgcn_rcpf(1.f + __expf(-ctx));
            f = ur + cw.y; sim = f * q.y; ctx = fmaf(sim, wsc, wb);
            o.y = q.y * __builtin_amdgcn_rcpf(1.f + __expf(-ctx));
            f = ur + cw.z; sim = f * q.z; ctx = fmaf(sim, wsc, wb);
            o.z = q.z * __builtin_amdgcn_rcpf(1.f + __expf(-ctx));
            f = ur + cw.w; sim = f * q.w; ctx = fmaf(sim, wsc, wb);
            o.w = q.w * __builtin_amdgcn_rcpf(1.f + __expf(-ctx));
            __builtin_nontemporal_store(o,
                reinterpret_cast<vf4*>(out4 + base4 + t + k * TPB));
        }
    }
}

extern "C" void kernel_launch(void* const* d_in, const int* in_sizes, int n_in,
                              void* d_out, int out_size, void* d_ws, size_t ws_size,
                              hipStream_t stream) {
    const float* x      = (const float*)d_in[0];
    const float* weight = (const float*)d_in[1];
    const float* bias   = (const float*)d_in[2];
    const float* one_   = (const float*)d_in[3];
    const float* zero   = (const float*)d_in[4];
    const float* theta  = (const float*)d_in[5];
    const float* scale  = (const float*)d_in[6];
    float* out = (float*)d_out;

    k_fused<<<NBLK, TPB, 0, stream>>>((const float4*)x, weight, bias, one_, zero,
                                      theta, scale, (float4*)out);
}